// Round 10
// baseline (490.302 us; speedup 1.0000x reference)
//
#include <hip/hip_runtime.h>
#include <hip/hip_bf16.h>

typedef unsigned int u32;
typedef unsigned short u16;
typedef unsigned long long u64;

typedef __attribute__((ext_vector_type(8))) short bf16x8;
typedef __attribute__((ext_vector_type(4))) float f32x4;

// bf16 = top 16 bits of fp32; RNE pack
static __device__ __forceinline__ float bflo(u32 u) { return __uint_as_float(u << 16); }
static __device__ __forceinline__ float bfhi(u32 u) { return __uint_as_float(u & 0xFFFF0000u); }
static __device__ __forceinline__ float bf2f(u16 u) { return __uint_as_float((u32)u << 16); }
static __device__ __forceinline__ u32 f2bf(float f) {
    u32 u = __float_as_uint(f);
    return (u + 0x7FFFu + ((u >> 16) & 1u)) >> 16;
}
static __device__ __forceinline__ u32 packbf(float lo, float hi) {
    return f2bf(lo) | (f2bf(hi) << 16);
}
static __device__ __forceinline__ float ldf(const u16* p16, int idx, int isf32) {
    return isf32 ? ((const float*)p16)[idx] : bf2f(p16[idx]);
}
static __device__ __forceinline__ void load4(const u16* p, int q, int isf32, float* v) {
    if (isf32) {
        float4 t = ((const float4*)p)[q];
        v[0] = t.x; v[1] = t.y; v[2] = t.z; v[3] = t.w;
    } else {
        u32 a = ((const u32*)p)[q * 2], b = ((const u32*)p)[q * 2 + 1];
        v[0] = bflo(a); v[1] = bfhi(a); v[2] = bflo(b); v[3] = bfhi(b);
    }
}
static __device__ __forceinline__ float sanitize(float v, float code) {
    return (fabsf(v) < 1e30f) ? v : code;
}

static __device__ __forceinline__ float wave_sum(float v) {
#pragma unroll
    for (int o = 32; o; o >>= 1) v += __shfl_xor(v, o, 64);
    return v;
}
static __device__ __forceinline__ float group_sum(float v) {
#pragma unroll
    for (int o = 8; o; o >>= 1) v += __shfl_xor(v, o, 64);
    return v;
}

// ---------------- diagnostics / utility ----------------

__global__ void k_sentinel(float* __restrict__ out, int n, float val) {
    int i = blockIdx.x * blockDim.x + threadIdx.x;
    if (i < n) out[i] = val;
}

__global__ void k_zero_sniff(int* __restrict__ p, int n, const u16* __restrict__ x,
                             int* __restrict__ flag) {
    int i = blockIdx.x * blockDim.x + threadIdx.x;
    if (i < n) p[i] = 0;
    if (blockIdx.x == 0 && threadIdx.x < 64) {
        int lane = threadIdx.x;
        int wild = 0;
        for (int k = 0; k < 64; k++) {
            u32 u = x[lane * 64 + k];
            int e = (u >> 7) & 0xFF;
            if (e < 96 || e > 135) wild++;
        }
        float tot = wave_sum((float)wild);
        if (lane == 0) *flag = (tot > 200.f) ? 1 : 0;
    }
}

// ---------------- edge sort by key = dst*3 + fake ----------------

__global__ void k_hist3(const int* __restrict__ src, const int* __restrict__ dst,
                        const int* __restrict__ lab, int E, int* __restrict__ deg3) {
    int i = blockIdx.x * blockDim.x + threadIdx.x;
    if (i >= E) return;
    int s = src[i], d = dst[i];
    int sl = lab[s], dl = lab[d];
    int fake = (sl < 0 || dl < 0) ? 2 : ((sl != dl) ? 1 : 0);
    atomicAdd(&deg3[d * 3 + fake], 1);
}

// scan: block spans 2048 elements, thread t owns [t*8, t*8+8)
__global__ void k_scan_partial8(const int* __restrict__ deg, int n, int* __restrict__ bsum) {
    int t = threadIdx.x;
    int base = blockIdx.x * 2048 + t * 8;
    int s = 0;
#pragma unroll
    for (int j = 0; j < 8; j++) {
        int idx = base + j;
        if (idx < n) s += deg[idx];
    }
    __shared__ int sh[256];
    sh[t] = s;
    __syncthreads();
    for (int d = 128; d; d >>= 1) {
        if (t < d) sh[t] += sh[t + d];
        __syncthreads();
    }
    if (t == 0) bsum[blockIdx.x] = sh[0];
}

__global__ void k_scan_bsum(const int* __restrict__ bsum, int nb, int* __restrict__ boff) {
    int t = threadIdx.x;  // 256 threads
    int v = (t < nb) ? bsum[t] : 0;
    __shared__ int sh[256];
    sh[t] = v;
    __syncthreads();
    for (int d = 1; d < 256; d <<= 1) {
        int u = (t >= d) ? sh[t - d] : 0;
        __syncthreads();
        sh[t] += u;
        __syncthreads();
    }
    if (t < nb) boff[t] = sh[t] - v;  // exclusive
}

__global__ void k_scan_final8(const int* __restrict__ deg, int n, const int* __restrict__ boff,
                              int* __restrict__ offsets, int Etot) {
    int t = threadIdx.x;
    int base = blockIdx.x * 2048 + t * 8;
    int v[8];
    int s = 0;
#pragma unroll
    for (int j = 0; j < 8; j++) {
        int idx = base + j;
        v[j] = (idx < n) ? deg[idx] : 0;
        s += v[j];
    }
    __shared__ int sh[256];
    sh[t] = s;
    __syncthreads();
    for (int d = 1; d < 256; d <<= 1) {
        int u = (t >= d) ? sh[t - d] : 0;
        __syncthreads();
        sh[t] += u;
        __syncthreads();
    }
    int ex = sh[t] - s + boff[blockIdx.x];
#pragma unroll
    for (int j = 0; j < 8; j++) {
        int idx = base + j;
        if (idx < n) offsets[idx] = ex;
        ex += v[j];
    }
    if (blockIdx.x == 0 && t == 0) offsets[n] = Etot;
}

// scatter edges into (dst,fake)-sorted order; 8B payload: low=src|fake<<20, high=bf16 (vl,vh)
__global__ void k_scatter(const int* __restrict__ src, const int* __restrict__ dst,
                          const u16* __restrict__ avl, const u16* __restrict__ avh,
                          const int* __restrict__ lab, int E,
                          const int* __restrict__ off3, int* __restrict__ cursor3,
                          u64* __restrict__ epay, const int* __restrict__ flag) {
    int i = blockIdx.x * blockDim.x + threadIdx.x;
    if (i >= E) return;
    int isf32 = *flag;
    int s = src[i], d = dst[i];
    int sl = lab[s], dl = lab[d];
    int fake = (sl < 0 || dl < 0) ? 2 : ((sl != dl) ? 1 : 0);
    int b = d * 3 + fake;
    int pos = off3[b] + atomicAdd(&cursor3[b], 1);
    if ((unsigned)pos >= (unsigned)E) return;
    u32 lo32 = (u32)(s | (fake << 20));
    u32 hi32 = isf32 ? packbf(((const float*)avl)[i], ((const float*)avh)[i])
                     : ((u32)avl[i] | ((u32)avh[i] << 16));
    epay[pos] = ((u64)hi32 << 32) | lo32;
}

// ---------------- node degree sort (for wave load balance) ----------------

__global__ void k_dhist(const int* __restrict__ deg3, int N, int* __restrict__ dbins) {
    __shared__ u32 lh[256];
    int t = threadIdx.x;
    lh[t] = 0;
    __syncthreads();
    int i = blockIdx.x * 256 + t;
    if (i < N) {
        int d = deg3[i * 3] + deg3[i * 3 + 1] + deg3[i * 3 + 2];
        atomicAdd(&lh[min(d, 255)], 1u);
    }
    __syncthreads();
    if (lh[t]) atomicAdd(&dbins[t], (int)lh[t]);
}

__global__ void k_dscan(const int* __restrict__ dbins, int* __restrict__ dbase) {
    int t = threadIdx.x;  // 256
    int v = dbins[t];
    __shared__ int sh[256];
    sh[t] = v;
    __syncthreads();
    for (int d = 1; d < 256; d <<= 1) {
        int u = (t >= d) ? sh[t - d] : 0;
        __syncthreads();
        sh[t] += u;
        __syncthreads();
    }
    dbase[t] = sh[t] - v;  // exclusive
}

__global__ void k_dscatter(const int* __restrict__ deg3, int N, const int* __restrict__ dbase,
                           int* __restrict__ dcur, int* __restrict__ perm) {
    __shared__ u32 lh[256], lrank[256], gbase[256];
    int t = threadIdx.x;
    lh[t] = 0;
    lrank[t] = 0;
    __syncthreads();
    int i = blockIdx.x * 256 + t;
    int b = -1;
    if (i < N) {
        int d = deg3[i * 3] + deg3[i * 3 + 1] + deg3[i * 3 + 2];
        b = min(d, 255);
        atomicAdd(&lh[b], 1u);
    }
    __syncthreads();
    if (lh[t]) gbase[t] = (u32)atomicAdd(&dcur[t], (int)lh[t]);
    __syncthreads();
    if (b >= 0) {
        u32 r = atomicAdd(&lrank[b], 1u);
        int pos = dbase[b] + (int)gbase[b] + (int)r;
        if ((unsigned)pos < (unsigned)N) perm[pos] = i;
    }
}

// ---------------- phase A: x @ {W_low, W_high, W_mlp} via MFMA ----------------

__global__ void k_prepB(const u16* __restrict__ wl, const u16* __restrict__ wh,
                        const u16* __restrict__ wm, u16* __restrict__ Bpack,
                        const int* __restrict__ flag) {
    int isf32 = *flag;
    for (int idx = threadIdx.x; idx < 12 * 2 * 64; idx += 256) {
        int slot = idx >> 6;   // 0..23 = ct*2+c
        int ln = idx & 63;
        int ct = slot >> 1, c = slot & 1;
        int mat = ct >> 2;
        const u16* W = (mat == 0) ? wl : (mat == 1) ? wh : wm;
        int col = (ct & 3) * 16 + (ln & 15);
        int kbase = c * 32 + (ln >> 4) * 8;
        u16* dst = Bpack + (size_t)idx * 8;
#pragma unroll
        for (int j = 0; j < 8; j++) dst[j] = (u16)f2bf(ldf(W, (kbase + j) * 64 + col, isf32));
    }
}

__launch_bounds__(256) __global__
void k_gemm_mfma(const u16* __restrict__ x, const u16* __restrict__ Bpack, int N,
                 u32* __restrict__ xwlh, float* __restrict__ omlp,
                 const int* __restrict__ flag) {
    int isf32 = *flag;
    int lane = threadIdx.x & 63;
    int wv = (blockIdx.x * 256 + threadIdx.x) >> 6;
    int nw = gridDim.x * 4;
    int m = lane & 15, quad = lane >> 4;
    int ntiles = (N + 15) >> 4;
    for (int tile = wv; tile < ntiles; tile += nw) {
        int r0 = tile * 16;
        int arow = min(r0 + m, N - 1);
        bf16x8 a[2];
#pragma unroll
        for (int c = 0; c < 2; c++) {
            int base = arow * 64 + c * 32 + quad * 8;
            if (isf32) {
                const float* xf = (const float*)x;
#pragma unroll
                for (int j = 0; j < 8; j++) a[c][j] = (short)f2bf(xf[base + j]);
            } else {
#pragma unroll
                for (int j = 0; j < 8; j++) a[c][j] = (short)x[base + j];
            }
        }
        f32x4 acc[12];
#pragma unroll
        for (int t = 0; t < 12; t++) acc[t] = (f32x4){0.f, 0.f, 0.f, 0.f};
#pragma unroll
        for (int t = 0; t < 12; t++) {
#pragma unroll
            for (int c = 0; c < 2; c++) {
                bf16x8 b = *(const bf16x8*)(Bpack + (size_t)((t * 2 + c) * 64 + lane) * 8);
                acc[t] = __builtin_amdgcn_mfma_f32_16x16x32_bf16(a[c], b, acc[t], 0, 0, 0);
            }
        }
        // C/D: col = lane&15, row = quad*4 + reg
#pragma unroll
        for (int t = 0; t < 4; t++) {
#pragma unroll
            for (int r = 0; r < 4; r++) {
                int row = r0 + quad * 4 + r;
                if (row < N) {
                    int o = row * 64 + t * 16 + m;
                    xwlh[o] = packbf(acc[t][r], acc[t + 4][r]);
                    omlp[o] = fmaxf(acc[t + 8][r], 0.f);
                }
            }
        }
    }
}

// ---------------- phase B: spmm + relu ----------------
// 4 nodes per wave (degree-matched via perm); 16-lane group owns one node's row.

__launch_bounds__(256) __global__
void k_spmm4n(const u32* __restrict__ xwlh, const u64* __restrict__ epay,
              const int* __restrict__ off3, const int* __restrict__ perm, int N, int E,
              u32* __restrict__ outlh) {
    int lane = threadIdx.x & 63;
    int gwave = blockIdx.x * 4 + (threadIdx.x >> 6);
    int g = lane & 15, gi = lane >> 4;
    int nidx = gwave * 4 + gi;
    bool vn = nidx < N;
    int node = vn ? perm[nidx] : 0;
    int s = vn ? off3[node * 3] : 0;
    int e = vn ? off3[node * 3 + 3] : 0;
    int deg = e - s;
    int md = deg;
    md = max(md, __shfl_xor(md, 16, 64));
    md = max(md, __shfl_xor(md, 32, 64));
    int Nm1 = N - 1, Em1 = E - 1;
    float aL[4] = {0.f, 0.f, 0.f, 0.f}, aH[4] = {0.f, 0.f, 0.f, 0.f};
    for (int t = 0; t < md; t += 2) {
#pragma unroll
        for (int u = 0; u < 2; u++) {
            int tt = t + u;
            int idx = min(max(s + min(tt, deg - 1), 0), Em1);
            u64 p = epay[idx];  // group-uniform address -> HW broadcast
            float w = (tt < deg) ? 1.f : 0.f;
            int sj = min((int)(p & 0xFFFFF), Nm1);
            u32 vv = (u32)(p >> 32);
            float vl = w * bflo(vv), vh = w * bfhi(vv);
            uint4 R = *((const uint4*)(xwlh + (size_t)sj * 64) + g);
            aL[0] += vl * bflo(R.x); aH[0] += vh * bfhi(R.x);
            aL[1] += vl * bflo(R.y); aH[1] += vh * bfhi(R.y);
            aL[2] += vl * bflo(R.z); aH[2] += vh * bfhi(R.z);
            aL[3] += vl * bflo(R.w); aH[3] += vh * bfhi(R.w);
        }
    }
    if (vn) {
        uint4 W;
        W.x = packbf(fmaxf(aL[0], 0.f), fmaxf(aH[0], 0.f));
        W.y = packbf(fmaxf(aL[1], 0.f), fmaxf(aH[1], 0.f));
        W.z = packbf(fmaxf(aL[2], 0.f), fmaxf(aH[2], 0.f));
        W.w = packbf(fmaxf(aL[3], 0.f), fmaxf(aH[3], 0.f));
        ((uint4*)(outlh + (size_t)node * 64))[g] = W;
    }
}

// ---------------- phase C+D fused: masked aggregation + attention ----------------
// edges pre-sorted by (dst,fake): three clean sub-ranges, 8 fmaf/edge, no masks.

static __device__ __forceinline__ void agg_class(const u32* __restrict__ outlh,
                                                 const u64* __restrict__ epay, int s, int e,
                                                 int g, int Nm1, int Em1, float* accL,
                                                 float* accH) {
    int deg = e - s;
    int md = deg;
    md = max(md, __shfl_xor(md, 16, 64));
    md = max(md, __shfl_xor(md, 32, 64));
    for (int t = 0; t < md; t += 2) {
#pragma unroll
        for (int u = 0; u < 2; u++) {
            int tt = t + u;
            int idx = min(max(s + min(tt, deg - 1), 0), Em1);
            u64 p = epay[idx];
            float w = (tt < deg) ? 1.f : 0.f;
            int sj = min((int)(p & 0xFFFFF), Nm1);
            uint4 R = *((const uint4*)(outlh + (size_t)sj * 64) + g);
            accL[0] = fmaf(w, bflo(R.x), accL[0]); accH[0] = fmaf(w, bfhi(R.x), accH[0]);
            accL[1] = fmaf(w, bflo(R.y), accL[1]); accH[1] = fmaf(w, bfhi(R.y), accH[1]);
            accL[2] = fmaf(w, bflo(R.z), accL[2]); accH[2] = fmaf(w, bfhi(R.z), accH[2]);
            accL[3] = fmaf(w, bflo(R.w), accL[3]); accH[3] = fmaf(w, bfhi(R.w), accH[3]);
        }
    }
}

__launch_bounds__(256) __global__
void k_agg4n(const u32* __restrict__ outlh, const u64* __restrict__ epay,
             const int* __restrict__ off3, const int* __restrict__ perm,
             const u16* __restrict__ aLF, const u16* __restrict__ aHF,
             const u16* __restrict__ aLB, const u16* __restrict__ aHB,
             const u16* __restrict__ aLU, const u16* __restrict__ aHU,
             const u16* __restrict__ aM, const u16* __restrict__ a7, int N, int E,
             float* __restrict__ out, const int* __restrict__ flag) {
    int isf32 = *flag;
    int lane = threadIdx.x & 63;
    int gwave = blockIdx.x * 4 + (threadIdx.x >> 6);
    int g = lane & 15, gi = lane >> 4;
    int nidx = gwave * 4 + gi;
    bool vn = nidx < N;
    int node = vn ? perm[nidx] : 0;
    int b0 = node * 3;
    int sHom = vn ? off3[b0] : 0;
    int sHet = vn ? off3[b0 + 1] : 0;
    int sUnk = vn ? off3[b0 + 2] : 0;
    int eAll = vn ? off3[b0 + 3] : 0;
    int Nm1 = N - 1, Em1 = E - 1;
    float heL[4] = {0, 0, 0, 0}, heH[4] = {0, 0, 0, 0};
    float hoL[4] = {0, 0, 0, 0}, hoH[4] = {0, 0, 0, 0};
    float unL[4] = {0, 0, 0, 0}, unH[4] = {0, 0, 0, 0};
    agg_class(outlh, epay, sHom, sHet, g, Nm1, Em1, hoL, hoH);
    agg_class(outlh, epay, sHet, sUnk, g, Nm1, Em1, heL, heH);
    agg_class(outlh, epay, sUnk, eAll, g, Nm1, Em1, unL, unH);

    float vLF[4], vHF[4], vLB[4], vHB[4], vLU[4], vHU[4], vM[4];
    load4(aLF, g, isf32, vLF);
    load4(aHF, g, isf32, vHF);
    load4(aLB, g, isf32, vLB);
    load4(aHB, g, isf32, vHB);
    load4(aLU, g, isf32, vLU);
    load4(aHU, g, isf32, vHU);
    load4(aM, g, isf32, vM);
    float mvv[4] = {0.f, 0.f, 0.f, 0.f};
    if (vn) {
        float4 MV = ((const float4*)(out + (size_t)node * 64))[g];  // omlp staged in d_out
        mvv[0] = MV.x; mvv[1] = MV.y; mvv[2] = MV.z; mvv[3] = MV.w;
    }

    float p0 = 0, p1 = 0, p2 = 0, p3 = 0, p4 = 0, p5 = 0, p6 = 0;
#pragma unroll
    for (int k = 0; k < 4; k++) {
        p0 += heL[k] * vLF[k];
        p1 += heH[k] * vHF[k];
        p2 += hoL[k] * vLB[k];
        p3 += hoH[k] * vHB[k];
        p4 += unL[k] * vLU[k];
        p5 += unH[k] * vHU[k];
        p6 += mvv[k] * vM[k];
    }
    float d0 = group_sum(p0), d1 = group_sum(p1), d2 = group_sum(p2), d3 = group_sum(p3);
    float d4 = group_sum(p4), d5 = group_sum(p5), d6 = group_sum(p6);

    float f[7];
    f[0] = 1.f / (1.f + expf(-d0));
    f[1] = 1.f / (1.f + expf(-d1));
    f[2] = 1.f / (1.f + expf(-d2));
    f[3] = 1.f / (1.f + expf(-d3));
    f[4] = 1.f / (1.f + expf(-d4));
    f[5] = 1.f / (1.f + expf(-d5));
    f[6] = 1.f / (1.f + expf(-d6));

    float z[7];
#pragma unroll
    for (int jj = 0; jj < 7; jj++) {
        float acc = 0.f;
#pragma unroll
        for (int i = 0; i < 7; i++) acc += f[i] * ldf(a7, i * 7 + jj, isf32);
        z[jj] = acc * (1.f / 7.f);
    }
    float m = z[0];
#pragma unroll
    for (int jj = 1; jj < 7; jj++) m = fmaxf(m, z[jj]);
    float wsum = 0.f;
    float wv[7];
#pragma unroll
    for (int jj = 0; jj < 7; jj++) { wv[jj] = expf(z[jj] - m); wsum += wv[jj]; }
    float s7 = 7.f / wsum;

    if (vn) {
        float4 W;
        float o0 = wv[0] * heL[0] + wv[1] * heH[0] + wv[2] * hoL[0] + wv[3] * hoH[0] +
                   wv[4] * unL[0] + wv[5] * unH[0] + wv[6] * mvv[0];
        float o1 = wv[0] * heL[1] + wv[1] * heH[1] + wv[2] * hoL[1] + wv[3] * hoH[1] +
                   wv[4] * unL[1] + wv[5] * unH[1] + wv[6] * mvv[1];
        float o2 = wv[0] * heL[2] + wv[1] * heH[2] + wv[2] * hoL[2] + wv[3] * hoH[2] +
                   wv[4] * unL[2] + wv[5] * unH[2] + wv[6] * mvv[2];
        float o3 = wv[0] * heL[3] + wv[1] * heH[3] + wv[2] * hoL[3] + wv[3] * hoH[3] +
                   wv[4] * unL[3] + wv[5] * unH[3] + wv[6] * mvv[3];
        W.x = sanitize(o0 * s7, 333.f);
        W.y = sanitize(o1 * s7, 333.f);
        W.z = sanitize(o2 * s7, 333.f);
        W.w = sanitize(o3 * s7, 333.f);
        ((float4*)(out + (size_t)node * 64))[g] = W;
    }
}

// ---------------- launcher ----------------

extern "C" void kernel_launch(void* const* d_in, const int* in_sizes, int n_in, void* d_out,
                              int out_size, void* d_ws, size_t ws_size, hipStream_t stream) {
    const u16* x = (const u16*)d_in[0];
    const u16* avl = (const u16*)d_in[1];
    const u16* avh = (const u16*)d_in[2];
    const u16* wl = (const u16*)d_in[3];
    const u16* wh = (const u16*)d_in[4];
    const u16* wm = (const u16*)d_in[5];
    const u16* aLF = (const u16*)d_in[6];
    const u16* aHF = (const u16*)d_in[7];
    const u16* aLB = (const u16*)d_in[8];
    const u16* aHB = (const u16*)d_in[9];
    const u16* aLU = (const u16*)d_in[10];
    const u16* aHU = (const u16*)d_in[11];
    const u16* aM = (const u16*)d_in[12];
    const u16* a7 = (const u16*)d_in[13];
    const int* esrc = (const int*)d_in[14];
    const int* edst = (const int*)d_in[15];
    const int* lab = (const int*)d_in[16];
    float* out = (float*)d_out;

    const int N = in_sizes[0] / 64;
    const int E = in_sizes[1];
    const int n3 = 3 * N;

    char* w = (char*)d_ws;
    size_t off = 0;
    auto alloc = [&](size_t bytes) -> char* {
        char* p = w + off;
        off += (bytes + 255) & ~(size_t)255;
        return p;
    };
    int* flag = (int*)alloc(256);
    int* off3 = (int*)alloc((size_t)(n3 + 1) * 4);
    int* zeroreg = (int*)alloc((size_t)(2 * n3 + 512) * 4);  // deg3 | cursor3 | dbins | dcur
    int* bsum = (int*)alloc(256 * 4);
    int* boff = (int*)alloc(256 * 4);
    int* dbase = (int*)alloc(256 * 4);
    int* perm = (int*)alloc((size_t)N * 4);
    u16* Bpack = (u16*)alloc(12 * 2 * 64 * 8 * 2);
    u64* epay = (u64*)alloc((size_t)E * 8);
    u32* xwlh = (u32*)alloc((size_t)N * 64 * 4);
    u32* outlh = (u32*)alloc((size_t)N * 64 * 4);

    if (ws_size < off) {
        k_sentinel<<<(out_size + 255) / 256, 256, 0, stream>>>(out, out_size, 1000.0f);
        return;
    }

    int* deg3 = zeroreg;
    int* cursor3 = zeroreg + n3;
    int* dbins = zeroreg + 2 * n3;
    int* dcur = zeroreg + 2 * n3 + 256;
    int nzero = 2 * n3 + 512;
    int NB3 = (n3 + 2047) / 2048;  // 147 for N=100000; must be <= 256

    k_zero_sniff<<<(nzero + 255) / 256, 256, 0, stream>>>(zeroreg, nzero, x, flag);
    k_hist3<<<(E + 255) / 256, 256, 0, stream>>>(esrc, edst, lab, E, deg3);
    k_scan_partial8<<<NB3, 256, 0, stream>>>(deg3, n3, bsum);
    k_scan_bsum<<<1, 256, 0, stream>>>(bsum, NB3, boff);
    k_scan_final8<<<NB3, 256, 0, stream>>>(deg3, n3, boff, off3, E);
    k_scatter<<<(E + 255) / 256, 256, 0, stream>>>(esrc, edst, avl, avh, lab, E, off3, cursor3,
                                                   epay, flag);

    int NBn = (N + 255) / 256;
    k_dhist<<<NBn, 256, 0, stream>>>(deg3, N, dbins);
    k_dscan<<<1, 256, 0, stream>>>(dbins, dbase);
    k_dscatter<<<NBn, 256, 0, stream>>>(deg3, N, dbase, dcur, perm);

    k_prepB<<<1, 256, 0, stream>>>(wl, wh, wm, Bpack, flag);
    int ntiles = (N + 15) / 16;
    int gemmBlocks = (ntiles + 3) / 4;
    k_gemm_mfma<<<gemmBlocks, 256, 0, stream>>>(x, Bpack, N, xwlh, out /* omlp in d_out */, flag);

    int nodeBlocks = (N + 15) / 16;  // 16 nodes per block (4 waves x 4 nodes)
    k_spmm4n<<<nodeBlocks, 256, 0, stream>>>(xwlh, epay, off3, perm, N, E, outlh);
    k_agg4n<<<nodeBlocks, 256, 0, stream>>>(outlh, epay, off3, perm, aLF, aHF, aLB, aHB, aLU,
                                            aHU, aM, a7, N, E, out, flag);
}